// Round 3
// baseline (335.199 us; speedup 1.0000x reference)
//
#include <hip/hip_runtime.h>
#include <hip/hip_fp16.h>
#include <stdint.h>

#define I_DIM 2048
#define O_DIM 2048
#define B_DIM 4096
#define KOUT 16
#define NBLK 512

typedef int i32x4 __attribute__((ext_vector_type(4)));
typedef float f32x4 __attribute__((ext_vector_type(4)));
typedef _Float16 f16x8 __attribute__((ext_vector_type(8)));

#define TO_LDS(p) ((__attribute__((address_space(3))) void*)(p))
#define TO_GLB(p) ((const __attribute__((address_space(1))) void*)(p))

// Hand-rolled grid barrier (graph-capture-safe, unlike hipLaunchCooperativeKernel).
// Requires all NBLK blocks co-resident: 512 blocks, 2/CU (64KB LDS, VGPR<=128 via
// __launch_bounds__(256,2)), 256 CUs. Sense-reversing via generation counter.
// Device-scope release/acquire => cross-XCD visibility of all prior writes.
__device__ __forceinline__ void grid_barrier(unsigned* cnt, unsigned* gen) {
  __syncthreads();
  if (threadIdx.x == 0) {
    __threadfence();
    unsigned g = __hip_atomic_load(gen, __ATOMIC_RELAXED, __HIP_MEMORY_SCOPE_AGENT);
    unsigned arrived = __hip_atomic_fetch_add(cnt, 1u, __ATOMIC_ACQ_REL, __HIP_MEMORY_SCOPE_AGENT);
    if (arrived == NBLK - 1) {
      __hip_atomic_store(cnt, 0u, __ATOMIC_RELAXED, __HIP_MEMORY_SCOPE_AGENT);
      __hip_atomic_fetch_add(gen, 1u, __ATOMIC_RELEASE, __HIP_MEMORY_SCOPE_AGENT);
    } else {
      long spin = 0;
      while (__hip_atomic_load(gen, __ATOMIC_ACQUIRE, __HIP_MEMORY_SCOPE_AGENT) == g) {
        if (++spin > 40000000L) break;   // failsafe: fail visibly, never hang
      }
    }
    __threadfence();
  }
  __syncthreads();
}

// Single fused kernel: colmax -> topk -> quant -> int8 GEMM + epilogue.
__global__ __launch_bounds__(256, 2) void mega_kernel(
    const float* __restrict__ X, const float* __restrict__ W,
    const float* __restrict__ biasg,
    unsigned* __restrict__ cm, unsigned* __restrict__ bar,
    int* __restrict__ idx, float* __restrict__ keep,
    signed char* __restrict__ xq, signed char* __restrict__ wq,
    float* __restrict__ xmax, float* __restrict__ wmax,
    _Float16* __restrict__ xunqh,   // [B][32] halves (k padded 16->32 w/ zeros)
    _Float16* __restrict__ wunqh,   // [O][32] halves
    float* __restrict__ out) {
  __shared__ __align__(16) signed char smem[2][32768];  // gemm double buffer
  __shared__ float wm_[4];
  __shared__ int wi_[4];
  __shared__ int sel;

  const int tid = threadIdx.x;
  const int bid = blockIdx.x;
  unsigned* bcnt = bar;
  unsigned* bgen = bar + 1;

  // ---------- P1: column absmax of W (cm pre-zeroed by hipMemsetAsync) ----------
  {
    const int cb = bid & 7;            // col block (256 cols)
    const int rc = bid >> 3;           // row chunk (32 rows), 0..63
    const int j = cb * 256 + tid;
    const float* p = W + (size_t)(rc * 32) * I_DIM + j;
    float m = 0.0f;
#pragma unroll 8
    for (int i = 0; i < 32; ++i)
      m = fmaxf(m, fabsf(p[(size_t)i * I_DIM]));
    atomicMax(cm + j, __float_as_uint(m));   // nonneg: uint order == float order
  }
  grid_barrier(bcnt, bgen);

  // ---------- P2: top-16 indices + keep mask (block 0 only) ----------
  if (bid == 0) {
    const float4* c4 = (const float4*)cm;
    float4 a = c4[tid * 2], b = c4[tid * 2 + 1];
    float v[8] = {a.x, a.y, a.z, a.w, b.x, b.y, b.z, b.w};
    for (int j = tid; j < I_DIM; j += 256) keep[j] = 1.0f;
    for (int k = 0; k < KOUT; ++k) {
      float m = v[0]; int mi = 0;
#pragma unroll
      for (int r = 1; r < 8; ++r) if (v[r] > m) { m = v[r]; mi = r; }
      int gi = tid * 8 + mi;
#pragma unroll
      for (int s = 32; s; s >>= 1) {
        float om = __shfl_down(m, s);
        int oi = __shfl_down(gi, s);
        if (om > m) { m = om; gi = oi; }
      }
      if ((tid & 63) == 0) { wm_[tid >> 6] = m; wi_[tid >> 6] = gi; }
      __syncthreads();
      if (tid == 0) {
        float bm = wm_[0]; int bi = wi_[0];
        for (int w2 = 1; w2 < 4; ++w2) if (wm_[w2] > bm) { bm = wm_[w2]; bi = wi_[w2]; }
        idx[k] = bi; keep[bi] = 0.0f; sel = bi;
      }
      __syncthreads();
      if (tid == (sel >> 3)) v[sel & 7] = -1.0f;
    }
  }
  grid_barrier(bcnt, bgen);

  // ---------- P3: quantize rows (u < O_DIM: W row u; else X row u-O_DIM) ----------
  for (int u = bid; u < O_DIM + B_DIM; u += NBLK) {   // 12 rows per block
    bool isW = u < O_DIM;
    int r = isW ? u : (u - O_DIM);
    const float* src = isW ? (W + (size_t)r * I_DIM) : (X + (size_t)r * I_DIM);
    const float4* s4 = (const float4*)src;
    const float4* k4 = (const float4*)keep;
    float4 v0 = s4[tid], v1 = s4[tid + 256];
    float4 k0 = k4[tid], k1 = k4[tid + 256];
    v0.x *= k0.x; v0.y *= k0.y; v0.z *= k0.z; v0.w *= k0.w;
    v1.x *= k1.x; v1.y *= k1.y; v1.z *= k1.z; v1.w *= k1.w;
    float m = fmaxf(fmaxf(fmaxf(fabsf(v0.x), fabsf(v0.y)), fmaxf(fabsf(v0.z), fabsf(v0.w))),
                    fmaxf(fmaxf(fabsf(v1.x), fabsf(v1.y)), fmaxf(fabsf(v1.z), fabsf(v1.w))));
#pragma unroll
    for (int s = 32; s; s >>= 1) m = fmaxf(m, __shfl_xor(m, s));
    if ((tid & 63) == 0) wm_[tid >> 6] = m;
    __syncthreads();
    m = fmaxf(fmaxf(wm_[0], wm_[1]), fmaxf(wm_[2], wm_[3]));
    float sc = 127.0f / m;                    // match ref: scale first, mul, trunc
    unsigned p0 = (unsigned char)(signed char)(int)(v0.x * sc)
                | ((unsigned)(unsigned char)(signed char)(int)(v0.y * sc) << 8)
                | ((unsigned)(unsigned char)(signed char)(int)(v0.z * sc) << 16)
                | ((unsigned)(unsigned char)(signed char)(int)(v0.w * sc) << 24);
    unsigned p1 = (unsigned char)(signed char)(int)(v1.x * sc)
                | ((unsigned)(unsigned char)(signed char)(int)(v1.y * sc) << 8)
                | ((unsigned)(unsigned char)(signed char)(int)(v1.z * sc) << 16)
                | ((unsigned)(unsigned char)(signed char)(int)(v1.w * sc) << 24);
    unsigned* qout = (unsigned*)(isW ? (wq + (size_t)r * I_DIM) : (xq + (size_t)r * I_DIM));
    qout[tid] = p0;
    qout[tid + 256] = p1;
    if (tid == 0) { if (isW) wmax[r] = m; else xmax[r] = m; }
    if (tid < KOUT) {
      float ov = src[idx[tid]];
      _Float16* u16 = isW ? (wunqh + (size_t)r * 32) : (xunqh + (size_t)r * 32);
      u16[tid] = (_Float16)ov;
      u16[tid + KOUT] = (_Float16)0.0f;
    }
    __syncthreads();    // protect wm_ reuse in next iteration
  }
  grid_barrier(bcnt, bgen);

  // ---------- P4: int8 GEMM (C = Xq * Wq^T) + fused MFMA epilogue ----------
  {
    constexpr int N = O_DIM, K = I_DIM;
    const int lane = tid & 63;
    const int wave = tid >> 6;
    const int wm = (wave & 1) * 64;
    const int wn = (wave >> 1) * 64;

    // XCD swizzle: 64 tiles per XCD, 8x8 regions (2MB A + 2MB B panels per L2)
    const int xcd = bid & 7;
    const int pos = bid >> 3;
    const int by = (xcd >> 1) * 8 + (pos >> 3);            // 0..31 (M tiles)
    const int bx = (xcd & 1) * 8 + (pos & 7);              // 0..15 (N tiles)
    const int m0 = by * 128;
    const int n0 = bx * 128;

    const int srow = tid >> 3;              // 0..31
    const int cslot = tid & 7;              // 0..7
    const int fm = lane & 15;
    const int q = lane >> 4;

    i32x4 acc[4][4] = {};

    // chunk swizzle: LDS slot (r, c) holds global 16B-chunk (c - (r>>1)) & 7
    auto stage = [&](int buf, int kt) {
      signed char* As = &smem[buf][0];
      signed char* Bs = &smem[buf][16384];
#pragma unroll
      for (int a = 0; a < 4; ++a) {
        const int row = a * 32 + srow;
        const int gch = (cslot - (row >> 1)) & 7;
        const signed char* ga = xq + (size_t)(m0 + row) * K + kt + gch * 16;
        const signed char* gb = wq + (size_t)(n0 + row) * K + kt + gch * 16;
        __builtin_amdgcn_global_load_lds(TO_GLB(ga), TO_LDS(As + a * 4096 + tid * 16), 16, 0, 0);
        __builtin_amdgcn_global_load_lds(TO_GLB(gb), TO_LDS(Bs + a * 4096 + tid * 16), 16, 0, 0);
      }
    };

    stage(0, 0);
    __syncthreads();

#pragma unroll 2
    for (int t = 0; t < K / 128; ++t) {                 // 16 iterations
      const int cur = t & 1;
      if (t < K / 128 - 1) stage(cur ^ 1, (t + 1) * 128);   // prefetch first
      const signed char* As = &smem[cur][0];
      const signed char* Bs = &smem[cur][16384];
#pragma unroll
      for (int s = 0; s < 2; ++s) {
        i32x4 af[4], bf[4];
        const int q8 = s * 4 + q;
#pragma unroll
        for (int i = 0; i < 4; ++i) {
          const int ra = wm + i * 16 + fm;
          af[i] = *(const i32x4*)(As + ra * 128 + (((q8 + (ra >> 1)) & 7) << 4));
          const int rb = wn + i * 16 + fm;
          bf[i] = *(const i32x4*)(Bs + rb * 128 + (((q8 + (rb >> 1)) & 7) << 4));
        }
#pragma unroll
        for (int i = 0; i < 4; ++i)
#pragma unroll
          for (int j = 0; j < 4; ++j)
            acc[i][j] = __builtin_amdgcn_mfma_i32_16x16x64_i8(af[i], bf[j], acc[i][j], 0, 0, 0);
      }
      __syncthreads();
    }

    // epilogue: dequant + fp16 round-trip + rank-16 outlier MFMA + bias
    f16x8 afh[4], bfh[4];
#pragma unroll
    for (int i = 0; i < 4; ++i)
      afh[i] = *(const f16x8*)(xunqh + (size_t)(m0 + wm + i * 16 + fm) * 32 + q * 8);
#pragma unroll
    for (int j = 0; j < 4; ++j)
      bfh[j] = *(const f16x8*)(wunqh + (size_t)(n0 + wn + j * 16 + fm) * 32 + q * 8);

#pragma unroll
    for (int i = 0; i < 4; ++i) {
      f32x4 xmv = *(const f32x4*)(xmax + m0 + wm + i * 16 + q * 4);
#pragma unroll
      for (int j = 0; j < 4; ++j) {
        int cl = n0 + wn + j * 16 + fm;
        float wmv = wmax[cl];
        float bv = biasg[cl];
        f32x4 c;
#pragma unroll
        for (int r = 0; r < 4; ++r) {
          float v = (float)acc[i][j][r] / 16129.0f;   // IEEE div, matches ref
          v = __half2float(__float2half(v));          // fp16 round-trip (RN)
          c[r] = v * (xmv[r] * wmv) + bv;
        }
        c = __builtin_amdgcn_mfma_f32_16x16x32_f16(afh[i], bfh[j], c, 0, 0, 0);
#pragma unroll
        for (int r = 0; r < 4; ++r)
          out[(size_t)(m0 + wm + i * 16 + q * 4 + r) * N + cl] = c[r];
      }
    }
  }
}

extern "C" void kernel_launch(void* const* d_in, const int* in_sizes, int n_in,
                              void* d_out, int out_size, void* d_ws, size_t ws_size,
                              hipStream_t stream) {
  const float* x    = (const float*)d_in[0];   // 4096 x 2048
  const float* w    = (const float*)d_in[1];   // 2048 x 2048
  const float* bias = (const float*)d_in[2];   // 2048
  float* out = (float*)d_out;
  char* ws = (char*)d_ws;

  unsigned* cm     = (unsigned*)(ws + 0);        // 8 KB
  unsigned* bar    = (unsigned*)(ws + 8192);     // 64 B  (cnt, gen)
  int* idx         = (int*)(ws + 8320);          // 128 B
  float* keep      = (float*)(ws + 8448);        // 8 KB
  float* w_max     = (float*)(ws + 16640);       // 8 KB
  float* x_max     = (float*)(ws + 24832);       // 16 KB
  _Float16* x_unqh = (_Float16*)(ws + 41216);    // 256 KB
  _Float16* w_unqh = (_Float16*)(ws + 303360);   // 128 KB
  signed char* w_q = (signed char*)(ws + 434432);   // 4 MB
  signed char* x_q = (signed char*)(ws + 4628736);  // 8 MB

  // zero cm (atomicMax identity) + barrier state; captured in the graph each replay
  hipMemsetAsync(ws, 0, 8256, stream);

  mega_kernel<<<dim3(NBLK), dim3(256), 0, stream>>>(
      x, w, bias, cm, bar, idx, keep, x_q, w_q, x_max, w_max,
      x_unqh, w_unqh, out);
}

// Round 4
// 298.220 us; speedup vs baseline: 1.1240x; 1.1240x over previous
//
#include <hip/hip_runtime.h>
#include <hip/hip_fp16.h>
#include <stdint.h>

#define I_DIM 2048
#define O_DIM 2048
#define B_DIM 4096
#define KOUT 16
#define NBLK 512

typedef int i32x4 __attribute__((ext_vector_type(4)));
typedef float f32x4 __attribute__((ext_vector_type(4)));
typedef _Float16 f16x8 __attribute__((ext_vector_type(8)));

#define TO_LDS(p) ((__attribute__((address_space(3))) void*)(p))
#define TO_GLB(p) ((const __attribute__((address_space(1))) void*)(p))

// Contention-free grid barrier (graph-capture-safe).
// Arrival: each block release-stores `target` into its own flag word (no RMW).
// Detection: block 0's 256 threads sweep the 512 flags (read-only, distinct lines),
// then one release-store to `gen` (its own cache line). Spinners poll gen with
// s_sleep backoff. Requires all NBLK blocks co-resident (512 = 256 CU x 2/CU,
// 64.5KB LDS, launch_bounds(256,2)); verified by round-3 pass + occupancy 23.6%.
__device__ __forceinline__ void grid_barrier(unsigned* flags, unsigned* gen,
                                             unsigned target) {
  __syncthreads();
  if (blockIdx.x != 0) {
    if (threadIdx.x == 0) {
      __threadfence();   // prior writes visible before flag release
      __hip_atomic_store(&flags[blockIdx.x], target, __ATOMIC_RELEASE,
                         __HIP_MEMORY_SCOPE_AGENT);
      long spin = 0;
      while (__hip_atomic_load(gen, __ATOMIC_ACQUIRE, __HIP_MEMORY_SCOPE_AGENT) < target) {
        __builtin_amdgcn_s_sleep(64);          // ~4096 cyc backoff: quiet fabric
        if (++spin > 2000000L) break;          // failsafe: never hang
      }
    }
  } else {
    __threadfence();
    const int i0 = threadIdx.x * 2, i1 = i0 + 1;
    long spin = 0;
    for (;;) {
      unsigned f0 = (i0 == 0) ? target
                  : __hip_atomic_load(&flags[i0], __ATOMIC_ACQUIRE, __HIP_MEMORY_SCOPE_AGENT);
      unsigned f1 = __hip_atomic_load(&flags[i1], __ATOMIC_ACQUIRE, __HIP_MEMORY_SCOPE_AGENT);
      if (f0 >= target && f1 >= target) break;
      __builtin_amdgcn_s_sleep(8);
      if (++spin > 8000000L) break;
    }
    __syncthreads();    // all pollers have observed arrival
    if (threadIdx.x == 0)
      __hip_atomic_store(gen, target, __ATOMIC_RELEASE, __HIP_MEMORY_SCOPE_AGENT);
  }
  __syncthreads();
}

// Single fused kernel: colmax -> topk -> quant -> int8 GEMM + epilogue.
__global__ __launch_bounds__(256, 2) void mega_kernel(
    const float* __restrict__ X, const float* __restrict__ W,
    const float* __restrict__ biasg,
    unsigned* __restrict__ cm, unsigned* __restrict__ flags,
    unsigned* __restrict__ gen,
    int* __restrict__ idx, float* __restrict__ keep,
    signed char* __restrict__ xq, signed char* __restrict__ wq,
    float* __restrict__ xmax, float* __restrict__ wmax,
    _Float16* __restrict__ xunqh,   // [B][32] halves (k padded 16->32 w/ zeros)
    _Float16* __restrict__ wunqh,   // [O][32] halves
    float* __restrict__ out) {
  __shared__ __align__(16) signed char smem[2][32768];  // gemm double buffer
  __shared__ float wm_[4];
  __shared__ int wi_[4];
  __shared__ int sel;

  const int tid = threadIdx.x;
  const int bid = blockIdx.x;

  // ---------- P1: column absmax of W (cm pre-zeroed by hipMemsetAsync) ----------
  {
    const int cb = bid & 7;            // col block (256 cols)
    const int rc = bid >> 3;           // row chunk (32 rows), 0..63
    const int j = cb * 256 + tid;
    const float* p = W + (size_t)(rc * 32) * I_DIM + j;
    float m = 0.0f;
#pragma unroll 8
    for (int i = 0; i < 32; ++i)
      m = fmaxf(m, fabsf(p[(size_t)i * I_DIM]));
    atomicMax(cm + j, __float_as_uint(m));   // nonneg: uint order == float order
  }
  grid_barrier(flags, gen, 1u);

  // ---------- P2: top-16 indices + keep mask (block 0 only) ----------
  if (bid == 0) {
    const float4* c4 = (const float4*)cm;
    float4 a = c4[tid * 2], b = c4[tid * 2 + 1];
    float v[8] = {a.x, a.y, a.z, a.w, b.x, b.y, b.z, b.w};
    for (int j = tid; j < I_DIM; j += 256) keep[j] = 1.0f;
    for (int k = 0; k < KOUT; ++k) {
      float m = v[0]; int mi = 0;
#pragma unroll
      for (int r = 1; r < 8; ++r) if (v[r] > m) { m = v[r]; mi = r; }
      int gi = tid * 8 + mi;
#pragma unroll
      for (int s = 32; s; s >>= 1) {
        float om = __shfl_down(m, s);
        int oi = __shfl_down(gi, s);
        if (om > m) { m = om; gi = oi; }
      }
      if ((tid & 63) == 0) { wm_[tid >> 6] = m; wi_[tid >> 6] = gi; }
      __syncthreads();
      if (tid == 0) {
        float bm = wm_[0]; int bi = wi_[0];
        for (int w2 = 1; w2 < 4; ++w2) if (wm_[w2] > bm) { bm = wm_[w2]; bi = wi_[w2]; }
        idx[k] = bi; keep[bi] = 0.0f; sel = bi;
      }
      __syncthreads();
      if (tid == (sel >> 3)) v[sel & 7] = -1.0f;
    }
  }
  grid_barrier(flags, gen, 2u);

  // ---------- P3: quantize rows (u < O_DIM: W row u; else X row u-O_DIM) ----------
  for (int u = bid; u < O_DIM + B_DIM; u += NBLK) {   // 12 rows per block
    bool isW = u < O_DIM;
    int r = isW ? u : (u - O_DIM);
    const float* src = isW ? (W + (size_t)r * I_DIM) : (X + (size_t)r * I_DIM);
    const float4* s4 = (const float4*)src;
    const float4* k4 = (const float4*)keep;
    float4 v0 = s4[tid], v1 = s4[tid + 256];
    float4 k0 = k4[tid], k1 = k4[tid + 256];
    v0.x *= k0.x; v0.y *= k0.y; v0.z *= k0.z; v0.w *= k0.w;
    v1.x *= k1.x; v1.y *= k1.y; v1.z *= k1.z; v1.w *= k1.w;
    float m = fmaxf(fmaxf(fmaxf(fabsf(v0.x), fabsf(v0.y)), fmaxf(fabsf(v0.z), fabsf(v0.w))),
                    fmaxf(fmaxf(fabsf(v1.x), fabsf(v1.y)), fmaxf(fabsf(v1.z), fabsf(v1.w))));
#pragma unroll
    for (int s = 32; s; s >>= 1) m = fmaxf(m, __shfl_xor(m, s));
    if ((tid & 63) == 0) wm_[tid >> 6] = m;
    __syncthreads();
    m = fmaxf(fmaxf(wm_[0], wm_[1]), fmaxf(wm_[2], wm_[3]));
    float sc = 127.0f / m;                    // match ref: scale first, mul, trunc
    unsigned p0 = (unsigned char)(signed char)(int)(v0.x * sc)
                | ((unsigned)(unsigned char)(signed char)(int)(v0.y * sc) << 8)
                | ((unsigned)(unsigned char)(signed char)(int)(v0.z * sc) << 16)
                | ((unsigned)(unsigned char)(signed char)(int)(v0.w * sc) << 24);
    unsigned p1 = (unsigned char)(signed char)(int)(v1.x * sc)
                | ((unsigned)(unsigned char)(signed char)(int)(v1.y * sc) << 8)
                | ((unsigned)(unsigned char)(signed char)(int)(v1.z * sc) << 16)
                | ((unsigned)(unsigned char)(signed char)(int)(v1.w * sc) << 24);
    unsigned* qout = (unsigned*)(isW ? (wq + (size_t)r * I_DIM) : (xq + (size_t)r * I_DIM));
    qout[tid] = p0;
    qout[tid + 256] = p1;
    if (tid == 0) { if (isW) wmax[r] = m; else xmax[r] = m; }
    if (tid < KOUT) {
      float ov = src[idx[tid]];
      _Float16* u16 = isW ? (wunqh + (size_t)r * 32) : (xunqh + (size_t)r * 32);
      u16[tid] = (_Float16)ov;
      u16[tid + KOUT] = (_Float16)0.0f;
    }
    __syncthreads();    // protect wm_ reuse in next iteration
  }
  grid_barrier(flags, gen, 3u);

  // ---------- P4: int8 GEMM (C = Xq * Wq^T) + fused MFMA epilogue ----------
  {
    constexpr int N = O_DIM, K = I_DIM;
    const int lane = tid & 63;
    const int wave = tid >> 6;
    const int wm = (wave & 1) * 64;
    const int wn = (wave >> 1) * 64;

    // XCD swizzle: 64 tiles per XCD, 8x8 regions (2MB A + 2MB B panels per L2)
    const int xcd = bid & 7;
    const int pos = bid >> 3;
    const int by = (xcd >> 1) * 8 + (pos >> 3);            // 0..31 (M tiles)
    const int bx = (xcd & 1) * 8 + (pos & 7);              // 0..15 (N tiles)
    const int m0 = by * 128;
    const int n0 = bx * 128;

    const int srow = tid >> 3;              // 0..31
    const int cslot = tid & 7;              // 0..7
    const int fm = lane & 15;
    const int q = lane >> 4;

    i32x4 acc[4][4] = {};

    // chunk swizzle: LDS slot (r, c) holds global 16B-chunk (c - (r>>1)) & 7
    auto stage = [&](int buf, int kt) {
      signed char* As = &smem[buf][0];
      signed char* Bs = &smem[buf][16384];
#pragma unroll
      for (int a = 0; a < 4; ++a) {
        const int row = a * 32 + srow;
        const int gch = (cslot - (row >> 1)) & 7;
        const signed char* ga = xq + (size_t)(m0 + row) * K + kt + gch * 16;
        const signed char* gb = wq + (size_t)(n0 + row) * K + kt + gch * 16;
        __builtin_amdgcn_global_load_lds(TO_GLB(ga), TO_LDS(As + a * 4096 + tid * 16), 16, 0, 0);
        __builtin_amdgcn_global_load_lds(TO_GLB(gb), TO_LDS(Bs + a * 4096 + tid * 16), 16, 0, 0);
      }
    };

    stage(0, 0);
    __syncthreads();

#pragma unroll 2
    for (int t = 0; t < K / 128; ++t) {                 // 16 iterations
      const int cur = t & 1;
      if (t < K / 128 - 1) stage(cur ^ 1, (t + 1) * 128);   // prefetch first
      const signed char* As = &smem[cur][0];
      const signed char* Bs = &smem[cur][16384];
#pragma unroll
      for (int s = 0; s < 2; ++s) {
        i32x4 af[4], bf[4];
        const int q8 = s * 4 + q;
#pragma unroll
        for (int i = 0; i < 4; ++i) {
          const int ra = wm + i * 16 + fm;
          af[i] = *(const i32x4*)(As + ra * 128 + (((q8 + (ra >> 1)) & 7) << 4));
          const int rb = wn + i * 16 + fm;
          bf[i] = *(const i32x4*)(Bs + rb * 128 + (((q8 + (rb >> 1)) & 7) << 4));
        }
#pragma unroll
        for (int i = 0; i < 4; ++i)
#pragma unroll
          for (int j = 0; j < 4; ++j)
            acc[i][j] = __builtin_amdgcn_mfma_i32_16x16x64_i8(af[i], bf[j], acc[i][j], 0, 0, 0);
      }
      __syncthreads();
    }

    // epilogue: dequant + fp16 round-trip + rank-16 outlier MFMA + bias
    f16x8 afh[4], bfh[4];
#pragma unroll
    for (int i = 0; i < 4; ++i)
      afh[i] = *(const f16x8*)(xunqh + (size_t)(m0 + wm + i * 16 + fm) * 32 + q * 8);
#pragma unroll
    for (int j = 0; j < 4; ++j)
      bfh[j] = *(const f16x8*)(wunqh + (size_t)(n0 + wn + j * 16 + fm) * 32 + q * 8);

#pragma unroll
    for (int i = 0; i < 4; ++i) {
      f32x4 xmv = *(const f32x4*)(xmax + m0 + wm + i * 16 + q * 4);
#pragma unroll
      for (int j = 0; j < 4; ++j) {
        int cl = n0 + wn + j * 16 + fm;
        float wmv = wmax[cl];
        float bv = biasg[cl];
        f32x4 c;
#pragma unroll
        for (int r = 0; r < 4; ++r) {
          float v = (float)acc[i][j][r] / 16129.0f;   // IEEE div, matches ref
          v = __half2float(__float2half(v));          // fp16 round-trip (RN)
          c[r] = v * (xmv[r] * wmv) + bv;
        }
        c = __builtin_amdgcn_mfma_f32_16x16x32_f16(afh[i], bfh[j], c, 0, 0, 0);
#pragma unroll
        for (int r = 0; r < 4; ++r)
          out[(size_t)(m0 + wm + i * 16 + q * 4 + r) * N + cl] = c[r];
      }
    }
  }
}

extern "C" void kernel_launch(void* const* d_in, const int* in_sizes, int n_in,
                              void* d_out, int out_size, void* d_ws, size_t ws_size,
                              hipStream_t stream) {
  const float* x    = (const float*)d_in[0];   // 4096 x 2048
  const float* w    = (const float*)d_in[1];   // 2048 x 2048
  const float* bias = (const float*)d_in[2];   // 2048
  float* out = (float*)d_out;
  char* ws = (char*)d_ws;

  unsigned* cm     = (unsigned*)(ws + 0);        // 8 KB
  unsigned* flags  = (unsigned*)(ws + 8192);     // 512 words = 2 KB
  unsigned* gen    = (unsigned*)(ws + 10240);    // own cache line (64 B)
  int* idx         = (int*)(ws + 10368);         // 128 B
  float* keep      = (float*)(ws + 10496);       // 8 KB
  float* w_max     = (float*)(ws + 18688);       // 8 KB
  float* x_max     = (float*)(ws + 26880);       // 16 KB
  _Float16* x_unqh = (_Float16*)(ws + 43264);    // 256 KB
  _Float16* w_unqh = (_Float16*)(ws + 305408);   // 128 KB
  signed char* w_q = (signed char*)(ws + 436480);   // 4 MB
  signed char* x_q = (signed char*)(ws + 4630784);  // 8 MB (total ~12.6 MB)

  // zero cm + flags + gen each replay (captured in graph)
  hipMemsetAsync(ws, 0, 10304, stream);

  mega_kernel<<<dim3(NBLK), dim3(256), 0, stream>>>(
      x, w, bias, cm, flags, gen, idx, keep, x_q, w_q, x_max, w_max,
      x_unqh, w_unqh, out);
}

// Round 5
// 138.526 us; speedup vs baseline: 2.4198x; 2.1528x over previous
//
#include <hip/hip_runtime.h>
#include <hip/hip_fp16.h>
#include <stdint.h>

#define I_DIM 2048
#define O_DIM 2048
#define B_DIM 4096
#define KOUT 16

typedef int i32x4 __attribute__((ext_vector_type(4)));
typedef float f32x4 __attribute__((ext_vector_type(4)));
typedef _Float16 f16x8 __attribute__((ext_vector_type(8)));

#define TO_LDS(p) ((__attribute__((address_space(3))) void*)(p))
#define TO_GLB(p) ((const __attribute__((address_space(1))) void*)(p))

// ---------------- Stage 1: column absmax of W (O_DIM x I_DIM) ----------------
// grid (8, 64): 512 blocks, 32 rows each.
__global__ void colmax_kernel(const float* __restrict__ W, unsigned* __restrict__ cm) {
  int j = blockIdx.x * 256 + threadIdx.x;       // column
  int i0 = blockIdx.y * 32;                     // row chunk
  float m = 0.0f;
  const float* p = W + (size_t)i0 * I_DIM + j;
#pragma unroll 8
  for (int i = 0; i < 32; ++i)
    m = fmaxf(m, fabsf(p[(size_t)i * I_DIM]));
  atomicMax(cm + j, __float_as_uint(m));        // nonneg floats: uint order == float order
}

// ---------------- Stage 2: per-block topk recompute + quantize 12 rows ----------------
// 512 blocks. Each block: top-16 from cm (deterministic, identical across blocks),
// keep mask in LDS, then 12 rows (4 waves x 3), one row per wave, no syncs in row loop.
__global__ __launch_bounds__(256) void quant_topk_kernel(
    const float* __restrict__ X, const float* __restrict__ W,
    const unsigned* __restrict__ cm,
    signed char* __restrict__ xq, signed char* __restrict__ wq,
    float* __restrict__ xmax, float* __restrict__ wmax,
    _Float16* __restrict__ xunqh,   // [B][32] halves (k padded 16->32 w/ zeros)
    _Float16* __restrict__ wunqh) { // [O][32] halves
  __shared__ float keepL[I_DIM];    // 8 KB
  __shared__ int idxL[KOUT];
  __shared__ float wm_[4];
  __shared__ int wi_[4];
  __shared__ int sel;

  const int t = threadIdx.x;

  // ---- local top-16 (identical algorithm & tie-breaks as the verified kernel) ----
  const float4* c4 = (const float4*)cm;
  float4 a = c4[t * 2], b = c4[t * 2 + 1];
  float v[8] = {a.x, a.y, a.z, a.w, b.x, b.y, b.z, b.w};
  {
    float4 one = {1.0f, 1.0f, 1.0f, 1.0f};
    ((float4*)keepL)[t] = one;
    ((float4*)keepL)[t + 256] = one;
  }
  for (int k = 0; k < KOUT; ++k) {
    float m = v[0]; int mi = 0;
#pragma unroll
    for (int r = 1; r < 8; ++r) if (v[r] > m) { m = v[r]; mi = r; }
    int gi = t * 8 + mi;
#pragma unroll
    for (int s = 32; s; s >>= 1) {
      float om = __shfl_down(m, s);
      int oi = __shfl_down(gi, s);
      if (om > m) { m = om; gi = oi; }
    }
    if ((t & 63) == 0) { wm_[t >> 6] = m; wi_[t >> 6] = gi; }
    __syncthreads();
    if (t == 0) {
      float bm = wm_[0]; int bi = wi_[0];
      for (int w2 = 1; w2 < 4; ++w2) if (wm_[w2] > bm) { bm = wm_[w2]; bi = wi_[w2]; }
      idxL[k] = bi; keepL[bi] = 0.0f; sel = bi;
    }
    __syncthreads();
    if (t == (sel >> 3)) v[sel & 7] = -1.0f;
  }
  __syncthreads();   // keepL / idxL fully visible to all waves

  // ---- quantize: one row per wave, 3 rounds (12 rows / 4 waves) ----
  const int wave = t >> 6;
  const int lane = t & 63;
  for (int rr = wave; rr < 12; rr += 4) {
    const int u = blockIdx.x * 12 + rr;         // 0..6143
    const bool isW = u < O_DIM;
    const int r = isW ? u : (u - O_DIM);
    const float* src = isW ? (W + (size_t)r * I_DIM) : (X + (size_t)r * I_DIM);
    const float4* s4 = (const float4*)src;
    const float4* k4 = (const float4*)keepL;

    float4 d[8];
    float mx = 0.0f;
#pragma unroll
    for (int i = 0; i < 8; ++i) {               // coalesced: float4 index i*64+lane
      float4 dv = s4[i * 64 + lane];
      float4 kk = k4[i * 64 + lane];
      dv.x *= kk.x; dv.y *= kk.y; dv.z *= kk.z; dv.w *= kk.w;
      d[i] = dv;
      mx = fmaxf(mx, fmaxf(fmaxf(fabsf(dv.x), fabsf(dv.y)),
                           fmaxf(fabsf(dv.z), fabsf(dv.w))));
    }
#pragma unroll
    for (int s = 32; s; s >>= 1) mx = fmaxf(mx, __shfl_xor(mx, s));
    const float sc = 127.0f / mx;               // match ref: scale first, mul, trunc
    unsigned* qout = (unsigned*)(isW ? (wq + (size_t)r * I_DIM) : (xq + (size_t)r * I_DIM));
#pragma unroll
    for (int i = 0; i < 8; ++i) {
      unsigned p = (unsigned char)(signed char)(int)(d[i].x * sc)
                 | ((unsigned)(unsigned char)(signed char)(int)(d[i].y * sc) << 8)
                 | ((unsigned)(unsigned char)(signed char)(int)(d[i].z * sc) << 16)
                 | ((unsigned)(unsigned char)(signed char)(int)(d[i].w * sc) << 24);
      qout[i * 64 + lane] = p;
    }
    if (lane == 0) { if (isW) wmax[r] = mx; else xmax[r] = mx; }
    if (lane < KOUT) {
      float ov = src[idxL[lane]];
      _Float16* u16 = isW ? (wunqh + (size_t)r * 32) : (xunqh + (size_t)r * 32);
      u16[lane] = (_Float16)ov;
      u16[lane + KOUT] = (_Float16)0.0f;        // zero-pad k 16..31
    }
  }
}

// ---------------- Stage 3: int8 GEMM (C = Xq * Wq^T) + fused MFMA epilogue ----------------
// BK=128, double-buffered LDS, prefetch-before-compute, one barrier per K-chunk,
// XCD-aware block swizzle. Verified structure (rounds 1/3/4).
__global__ __launch_bounds__(256, 2) void gemm_kernel(
    const signed char* __restrict__ Aq,   // M x K (x_q)
    const signed char* __restrict__ Bq,   // N x K (w_q)
    const float* __restrict__ xmaxg,      // M
    const float* __restrict__ wmaxg,      // N
    const _Float16* __restrict__ xunqh,   // M x 32
    const _Float16* __restrict__ wunqh,   // N x 32
    const float* __restrict__ biasg,      // N
    float* __restrict__ out) {            // M x N
  constexpr int N = O_DIM, K = I_DIM;
  __shared__ __align__(16) signed char smem[2][32768];  // per buf: As 16K | Bs 16K

  const int tid = threadIdx.x;
  const int lane = tid & 63;
  const int wave = tid >> 6;
  const int wm = (wave & 1) * 64;
  const int wn = (wave >> 1) * 64;

  // XCD swizzle: 64 tiles per XCD, 8x8 regions (2MB A + 2MB B panels per L2)
  const int lid = blockIdx.y * gridDim.x + blockIdx.x;   // 0..511
  const int xcd = lid & 7;
  const int pos = lid >> 3;                              // 0..63
  const int by = (xcd >> 1) * 8 + (pos >> 3);            // 0..31 (M tiles)
  const int bx = (xcd & 1) * 8 + (pos & 7);              // 0..15 (N tiles)
  const int m0 = by * 128;
  const int n0 = bx * 128;

  const int srow = tid >> 3;              // 0..31
  const int cslot = tid & 7;              // 0..7
  const int fm = lane & 15;
  const int q = lane >> 4;

  i32x4 acc[4][4] = {};

  // chunk swizzle: LDS slot (r, c) holds global 16B-chunk (c - (r>>1)) & 7
  auto stage = [&](int buf, int kt) {
    signed char* As = &smem[buf][0];
    signed char* Bs = &smem[buf][16384];
#pragma unroll
    for (int a = 0; a < 4; ++a) {
      const int row = a * 32 + srow;
      const int gch = (cslot - (row >> 1)) & 7;
      const signed char* ga = Aq + (size_t)(m0 + row) * K + kt + gch * 16;
      const signed char* gb = Bq + (size_t)(n0 + row) * K + kt + gch * 16;
      __builtin_amdgcn_global_load_lds(TO_GLB(ga), TO_LDS(As + a * 4096 + tid * 16), 16, 0, 0);
      __builtin_amdgcn_global_load_lds(TO_GLB(gb), TO_LDS(Bs + a * 4096 + tid * 16), 16, 0, 0);
    }
  };

  stage(0, 0);
  __syncthreads();

#pragma unroll 2
  for (int t = 0; t < K / 128; ++t) {                 // 16 iterations
    const int cur = t & 1;
    if (t < K / 128 - 1) stage(cur ^ 1, (t + 1) * 128);   // prefetch first
    const signed char* As = &smem[cur][0];
    const signed char* Bs = &smem[cur][16384];
#pragma unroll
    for (int s = 0; s < 2; ++s) {
      i32x4 af[4], bf[4];
      const int q8 = s * 4 + q;
#pragma unroll
      for (int i = 0; i < 4; ++i) {
        const int ra = wm + i * 16 + fm;
        af[i] = *(const i32x4*)(As + ra * 128 + (((q8 + (ra >> 1)) & 7) << 4));
        const int rb = wn + i * 16 + fm;
        bf[i] = *(const i32x4*)(Bs + rb * 128 + (((q8 + (rb >> 1)) & 7) << 4));
      }
#pragma unroll
      for (int i = 0; i < 4; ++i)
#pragma unroll
        for (int j = 0; j < 4; ++j)
          acc[i][j] = __builtin_amdgcn_mfma_i32_16x16x64_i8(af[i], bf[j], acc[i][j], 0, 0, 0);
    }
    __syncthreads();
  }

  // epilogue: dequant + fp16 round-trip + rank-16 outlier MFMA + bias
  f16x8 afh[4], bfh[4];
#pragma unroll
  for (int i = 0; i < 4; ++i)
    afh[i] = *(const f16x8*)(xunqh + (size_t)(m0 + wm + i * 16 + fm) * 32 + q * 8);
#pragma unroll
  for (int j = 0; j < 4; ++j)
    bfh[j] = *(const f16x8*)(wunqh + (size_t)(n0 + wn + j * 16 + fm) * 32 + q * 8);

#pragma unroll
  for (int i = 0; i < 4; ++i) {
    f32x4 xmv = *(const f32x4*)(xmaxg + m0 + wm + i * 16 + q * 4);
#pragma unroll
    for (int j = 0; j < 4; ++j) {
      int cl = n0 + wn + j * 16 + fm;
      float wmv = wmaxg[cl];
      float bv = biasg[cl];
      f32x4 c;
#pragma unroll
      for (int r = 0; r < 4; ++r) {
        float v = (float)acc[i][j][r] / 16129.0f;   // IEEE div, matches ref
        v = __half2float(__float2half(v));          // fp16 round-trip (RN)
        c[r] = v * (xmv[r] * wmv) + bv;
      }
      c = __builtin_amdgcn_mfma_f32_16x16x32_f16(afh[i], bfh[j], c, 0, 0, 0);
#pragma unroll
      for (int r = 0; r < 4; ++r)
        out[(size_t)(m0 + wm + i * 16 + q * 4 + r) * N + cl] = c[r];
    }
  }
}

extern "C" void kernel_launch(void* const* d_in, const int* in_sizes, int n_in,
                              void* d_out, int out_size, void* d_ws, size_t ws_size,
                              hipStream_t stream) {
  const float* x    = (const float*)d_in[0];   // 4096 x 2048
  const float* w    = (const float*)d_in[1];   // 2048 x 2048
  const float* bias = (const float*)d_in[2];   // 2048
  float* out = (float*)d_out;
  char* ws = (char*)d_ws;

  unsigned* cm     = (unsigned*)(ws + 0);          // 8 KB
  float* w_max     = (float*)(ws + 8192);          // 8 KB
  float* x_max     = (float*)(ws + 16384);         // 16 KB
  _Float16* x_unqh = (_Float16*)(ws + 32768);      // 256 KB
  _Float16* w_unqh = (_Float16*)(ws + 294912);     // 128 KB
  signed char* w_q = (signed char*)(ws + 425984);     // 4 MB
  signed char* x_q = (signed char*)(ws + 4620288);    // 8 MB (total ~12.4 MB)

  hipMemsetAsync(cm, 0, 8192, stream);
  colmax_kernel<<<dim3(8, 64), 256, 0, stream>>>(w, cm);
  quant_topk_kernel<<<512, 256, 0, stream>>>(x, w, cm, x_q, w_q,
                                             x_max, w_max, x_unqh, w_unqh);
  gemm_kernel<<<dim3(O_DIM / 128, B_DIM / 128), 256, 0, stream>>>(
      x_q, w_q, x_max, w_max, x_unqh, w_unqh, bias, out);
}